// Round 2
// baseline (82.140 us; speedup 1.0000x reference)
//
#include <hip/hip_runtime.h>

// CollapsePreventionLoss: B=64 batches, N=1024 atoms (3072 coords each).
// loss = sum_{i<j} max(2.9 - dist(i,j), 0)^2 / B
// Symmetric in (i,j) -> compute full i!=j matrix and halve.

constexpr int   NA    = 1024;   // atoms per batch
constexpr int   JCH   = 256;    // j-atoms staged per block
constexpr float MIN_D = 2.9f;

__global__ __launch_bounds__(256, 4)
void collapse_loss_kernel(const float* __restrict__ coords,
                          float* __restrict__ out)
{
    const int b   = blockIdx.x;   // 64 batches
    const int ic  = blockIdx.y;   // 4 i-chunks of 256
    const int jc  = blockIdx.z;   // 4 j-chunks of 256
    const int tid = threadIdx.x;  // 256 threads

    __shared__ float sx[JCH], sy[JCH], sz[JCH];

    const float* cb = coords + (size_t)b * (NA * 3);
    const int jbase = jc * JCH;

    // Stage this block's j-chunk into LDS (SoA). Strided global reads, but
    // it's 3 KB per block against L2-hot data -- negligible vs the 256-iter
    // compute loop.
    {
        const int ja = jbase + tid;
        sx[tid] = cb[3 * ja + 0];
        sy[tid] = cb[3 * ja + 1];
        sz[tid] = cb[3 * ja + 2];
    }

    // Each thread owns one i-atom in registers.
    const int i = ic * 256 + tid;
    const float xi = cb[3 * i + 0];
    const float yi = cb[3 * i + 1];
    const float zi = cb[3 * i + 2];

    __syncthreads();

    float acc = 0.0f;
    #pragma unroll 8
    for (int j = 0; j < JCH; ++j) {
        // sx/sy/sz[j] is wave-uniform -> LDS broadcast, conflict-free.
        const float dx = xi - sx[j];
        const float dy = yi - sy[j];
        const float dz = zi - sz[j];
        float ds = fmaf(dx, dx, fmaf(dy, dy, dz * dz)) + 1e-8f;
        float d  = __builtin_amdgcn_sqrtf(ds);
        float v  = fmaxf(MIN_D - d, 0.0f);
        float c  = v * v;
        if (i == jbase + j) c = 0.0f;   // exclude diagonal (dist ~= 1e-4)
        acc += c;
    }

    // wave (64-lane) butterfly reduction
    #pragma unroll
    for (int off = 1; off < 64; off <<= 1)
        acc += __shfl_xor(acc, off, 64);

    __shared__ float wsum[4];
    if ((tid & 63) == 0) wsum[tid >> 6] = acc;
    __syncthreads();
    if (tid == 0) {
        const float s = (wsum[0] + wsum[1]) + (wsum[2] + wsum[3]);
        // 0.5: each unordered pair counted twice; /64: divide by B.
        atomicAdd(out, s * (0.5f / 64.0f));
    }
}

extern "C" void kernel_launch(void* const* d_in, const int* in_sizes, int n_in,
                              void* d_out, int out_size, void* d_ws, size_t ws_size,
                              hipStream_t stream)
{
    const float* coords = (const float*)d_in[0];
    float* out = (float*)d_out;

    // d_out is poisoned 0xAA before every timed launch -- zero it first.
    hipMemsetAsync(out, 0, sizeof(float) * out_size, stream);

    dim3 grid(64, NA / 256, NA / JCH);   // 64 x 4 x 4 = 1024 blocks
    collapse_loss_kernel<<<grid, 256, 0, stream>>>(coords, out);
}

// Round 4
// 74.000 us; speedup vs baseline: 1.1100x; 1.1100x over previous
//
#include <hip/hip_runtime.h>

// CollapsePreventionLoss: B=64, N=1024 atoms/batch.
// loss = sum_{i<j} max(2.9 - dist(i,j), 0)^2 / B
// Full i x j matrix (incl. diagonal, no branch), halve, subtract analytic
// diagonal in the final reducer. Partials -> d_ws, reducer overwrites d_out
// (no memset in the timed graph -- the 4-byte fill cost ~40us!).

constexpr int   NA      = 1024;
constexpr int   NB      = 64;
constexpr int   JCH     = 128;              // j-atoms staged per block
constexpr int   THREADS = 256;
constexpr int   IPT     = 2;                // i-atoms per thread
constexpr int   ICH     = THREADS * IPT;    // 512 i-atoms per block
constexpr int   GRID_I  = NA / ICH;         // 2
constexpr int   GRID_J  = NA / JCH;         // 8
constexpr int   NPART   = NB * GRID_I * GRID_J;  // 1024 partials
constexpr float MIN_D   = 2.9f;

__global__ __launch_bounds__(THREADS, 4)
void pair_kernel(const float* __restrict__ coords, float* __restrict__ partials)
{
    const int b   = blockIdx.x;   // 64
    const int ic  = blockIdx.y;   // 2
    const int jc  = blockIdx.z;   // 8
    const int tid = threadIdx.x;

    __shared__ float sj[JCH * 3];   // AoS xyz, 1.5 KB

    const float* cb = coords + (size_t)b * (NA * 3);
    const float* cj = cb + jc * (JCH * 3);

    // coalesced staging of 384 contiguous floats
    sj[tid] = cj[tid];
    if (tid < JCH * 3 - THREADS) sj[THREADS + tid] = cj[THREADS + tid];

    // two i-atoms per thread, held in registers
    const int i0 = ic * ICH + tid;
    const int i1 = i0 + THREADS;
    const float x0 = cb[3*i0+0], y0 = cb[3*i0+1], z0 = cb[3*i0+2];
    const float x1 = cb[3*i1+0], y1 = cb[3*i1+1], z1 = cb[3*i1+2];

    __syncthreads();

    float acc0 = 0.f, acc1 = 0.f;
    #pragma unroll 8
    for (int j = 0; j < JCH; ++j) {
        // uniform consecutive LDS reads -> broadcast, merged into b128 by unroll
        const float xj = sj[3*j+0], yj = sj[3*j+1], zj = sj[3*j+2];
        {
            const float dx = x0-xj, dy = y0-yj, dz = z0-zj;
            const float ds = fmaf(dx,dx, fmaf(dy,dy, fmaf(dz,dz, 1e-8f)));
            const float v  = fmaxf(MIN_D - __builtin_amdgcn_sqrtf(ds), 0.f);
            acc0 = fmaf(v, v, acc0);
        }
        {
            const float dx = x1-xj, dy = y1-yj, dz = z1-zj;
            const float ds = fmaf(dx,dx, fmaf(dy,dy, fmaf(dz,dz, 1e-8f)));
            const float v  = fmaxf(MIN_D - __builtin_amdgcn_sqrtf(ds), 0.f);
            acc1 = fmaf(v, v, acc1);
        }
    }
    float acc = acc0 + acc1;

    #pragma unroll
    for (int off = 1; off < 64; off <<= 1)
        acc += __shfl_xor(acc, off, 64);

    __shared__ float wsum[THREADS / 64];
    if ((tid & 63) == 0) wsum[tid >> 6] = acc;
    __syncthreads();
    if (tid == 0) {
        float s = 0.f;
        #pragma unroll
        for (int w = 0; w < THREADS / 64; ++w) s += wsum[w];
        partials[(b * GRID_I + ic) * GRID_J + jc] = s;
    }
}

__global__ __launch_bounds__(256)
void reduce_kernel(const float* __restrict__ partials, float* __restrict__ out)
{
    const int tid = threadIdx.x;
    float s = 0.f;
    #pragma unroll
    for (int k = tid; k < NPART; k += 256) s += partials[k];
    #pragma unroll
    for (int off = 1; off < 64; off <<= 1)
        s += __shfl_xor(s, off, 64);
    __shared__ float wsum[4];
    if ((tid & 63) == 0) wsum[tid >> 6] = s;
    __syncthreads();
    if (tid == 0) {
        float tot = (wsum[0] + wsum[1]) + (wsum[2] + wsum[3]);
        // Subtract diagonal terms, computed with the SAME instruction
        // sequence the main loop used for i==j (ds == 1e-8f exactly).
        const float d0 = __builtin_amdgcn_sqrtf(1e-8f);
        const float v0 = fmaxf(MIN_D - d0, 0.f);
        const float cd = v0 * v0;
        tot -= (float)(NB * NA) * cd;
        // 0.5: unordered pairs counted twice; /64: divide by B.
        out[0] = tot * (0.5f / (float)NB);
    }
}

extern "C" void kernel_launch(void* const* d_in, const int* in_sizes, int n_in,
                              void* d_out, int out_size, void* d_ws, size_t ws_size,
                              hipStream_t stream)
{
    const float* coords = (const float*)d_in[0];
    float* partials = (float*)d_ws;
    float* out = (float*)d_out;

    dim3 grid(NB, GRID_I, GRID_J);   // 64 x 2 x 8 = 1024 blocks
    pair_kernel<<<grid, THREADS, 0, stream>>>(coords, partials);
    reduce_kernel<<<1, 256, 0, stream>>>(partials, out);
}

// Round 6
// 73.228 us; speedup vs baseline: 1.1217x; 1.0105x over previous
//
#include <hip/hip_runtime.h>

// CollapsePreventionLoss: B=64, N=1024 atoms/batch.
// loss = sum_{i<j} max(2.9 - dist(i,j), 0)^2 / B
// Full i x j matrix (incl. diagonal), halve, subtract analytic diagonal in
// the reducer. IPT=4 i-atoms/thread; j-chunk staged in LDS as float4 so each
// j is ONE ds_read_b128 broadcast (round-4 AoS b32 reads made the LDS pipe,
// not the VALU, the bottleneck).

constexpr int   NA      = 1024;
constexpr int   NB      = 64;
constexpr int   JCH     = 64;               // j-atoms per block
constexpr int   THREADS = 256;
constexpr int   IPT     = 4;                // i-atoms per thread (covers all 1024)
constexpr int   GRID_J  = NA / JCH;         // 16
constexpr int   NPART   = NB * GRID_J;      // 1024 partials
constexpr float MIN_D   = 2.9f;

__global__ __launch_bounds__(THREADS, 4)
void pair_kernel(const float* __restrict__ coords, float* __restrict__ partials)
{
    const int b   = blockIdx.x;   // 64
    const int jc  = blockIdx.y;   // 16
    const int tid = threadIdx.x;

    __shared__ float4 sj[JCH];    // 1 KB

    const float* cb = coords + (size_t)b * (NA * 3);

    if (tid < JCH) {
        const int ja = jc * JCH + tid;
        sj[tid] = make_float4(cb[3*ja+0], cb[3*ja+1], cb[3*ja+2], 0.f);
    }

    // four i-atoms per thread: tid, tid+256, tid+512, tid+768
    float xi[IPT], yi[IPT], zi[IPT];
    #pragma unroll
    for (int k = 0; k < IPT; ++k) {
        const int i = k * THREADS + tid;
        xi[k] = cb[3*i+0]; yi[k] = cb[3*i+1]; zi[k] = cb[3*i+2];
    }

    __syncthreads();

    float acc[IPT] = {0.f, 0.f, 0.f, 0.f};
    #pragma unroll 8
    for (int j = 0; j < JCH; ++j) {
        const float4 aj = sj[j];   // one b128 broadcast, conflict-free
        #pragma unroll
        for (int k = 0; k < IPT; ++k) {
            const float dx = xi[k] - aj.x;
            const float dy = yi[k] - aj.y;
            const float dz = zi[k] - aj.z;
            const float ds = fmaf(dx,dx, fmaf(dy,dy, fmaf(dz,dz, 1e-8f)));
            const float v  = fmaxf(MIN_D - __builtin_amdgcn_sqrtf(ds), 0.f);
            acc[k] = fmaf(v, v, acc[k]);
        }
    }
    float acc_t = (acc[0] + acc[1]) + (acc[2] + acc[3]);

    #pragma unroll
    for (int off = 1; off < 64; off <<= 1)
        acc_t += __shfl_xor(acc_t, off, 64);

    __shared__ float wsum[THREADS / 64];
    if ((tid & 63) == 0) wsum[tid >> 6] = acc_t;
    __syncthreads();
    if (tid == 0) {
        float s = 0.f;
        #pragma unroll
        for (int w = 0; w < THREADS / 64; ++w) s += wsum[w];
        partials[b * GRID_J + jc] = s;
    }
}

__global__ __launch_bounds__(256)
void reduce_kernel(const float* __restrict__ partials, float* __restrict__ out)
{
    const int tid = threadIdx.x;
    float s = 0.f;
    #pragma unroll
    for (int k = tid; k < NPART; k += 256) s += partials[k];
    #pragma unroll
    for (int off = 1; off < 64; off <<= 1)
        s += __shfl_xor(s, off, 64);
    __shared__ float wsum[4];
    if ((tid & 63) == 0) wsum[tid >> 6] = s;
    __syncthreads();
    if (tid == 0) {
        float tot = (wsum[0] + wsum[1]) + (wsum[2] + wsum[3]);
        // Subtract diagonal terms (i==j), computed with the SAME instruction
        // sequence as the main loop (ds == 1e-8f exactly).
        const float d0 = __builtin_amdgcn_sqrtf(1e-8f);
        const float v0 = fmaxf(MIN_D - d0, 0.f);
        const float cd = v0 * v0;
        tot -= (float)(NB * NA) * cd;
        // 0.5: unordered pairs counted twice; /64: divide by B.
        out[0] = tot * (0.5f / (float)NB);
    }
}

extern "C" void kernel_launch(void* const* d_in, const int* in_sizes, int n_in,
                              void* d_out, int out_size, void* d_ws, size_t ws_size,
                              hipStream_t stream)
{
    const float* coords = (const float*)d_in[0];
    float* partials = (float*)d_ws;
    float* out = (float*)d_out;

    dim3 grid(NB, GRID_J);   // 64 x 16 = 1024 blocks
    pair_kernel<<<grid, THREADS, 0, stream>>>(coords, partials);
    reduce_kernel<<<1, 256, 0, stream>>>(partials, out);
}

// Round 10
// 68.568 us; speedup vs baseline: 1.1979x; 1.0680x over previous
//
#include <hip/hip_runtime.h>

// CollapsePreventionLoss: B=64, N=1024 atoms/batch.
// loss = sum_{i<j} max(2.9 - dist(i,j), 0)^2 / B
//
// Triangular tile decomposition (each unordered pair computed EXACTLY once):
//   8 tiles of 128 atoms.
//   - 28 cross blocks (ti<tj): full 128x128 cross product. 256 threads =
//     2 per i-atom; thread-half h picks j-range [h*64, h*64+64) so the
//     LDS j-read stays wave-uniform (broadcast, conflict-free).
//   - 8 diag blocks: pairs (i, i+d) within the tile; h=0 -> d=1..64,
//     h=1 -> d=65..127; j>=128 masked off. Per-lane stride-1 float4 reads.
// Pairs counted once -> final scale is 1/B, no diagonal correction.

constexpr int   NA     = 1024;
constexpr int   NB     = 64;
constexpr int   TILE   = 128;
constexpr int   NT     = NA / TILE;          // 8
constexpr int   NCROSS = NT * (NT - 1) / 2;  // 28
constexpr int   NPAIR  = NCROSS + NT;        // 36 blocks per batch
constexpr int   NPART  = NB * NPAIR;         // 2304 partials
constexpr float MIN_D  = 2.9f;

static __device__ const int TI_[NCROSS] = {
    0,0,0,0,0,0,0, 1,1,1,1,1,1, 2,2,2,2,2, 3,3,3,3, 4,4,4, 5,5, 6};
static __device__ const int TJ_[NCROSS] = {
    1,2,3,4,5,6,7, 2,3,4,5,6,7, 3,4,5,6,7, 4,5,6,7, 5,6,7, 6,7, 7};

__global__ __launch_bounds__(256, 4)
void pair_kernel(const float* __restrict__ coords, float* __restrict__ partials)
{
    const int b = blockIdx.x;       // 64
    const int p = blockIdx.y;       // 36
    const int t = threadIdx.x;
    const int l = t & 127;          // lane-in-tile
    const int h = t >> 7;           // thread-half (wave-uniform)

    __shared__ float4 sj[TILE];     // 2 KB

    const float* cb = coords + (size_t)b * (NA * 3);

    const bool diag = (p >= NCROSS);
    const int ti = diag ? (p - NCROSS) : TI_[p];
    const int tj = diag ? (p - NCROSS) : TJ_[p];

    if (t < TILE) {
        const int ja = tj * TILE + t;
        sj[t] = make_float4(cb[3*ja+0], cb[3*ja+1], cb[3*ja+2], 0.f);
    }

    const int i = ti * TILE + l;
    const float xi = cb[3*i+0], yi = cb[3*i+1], zi = cb[3*i+2];

    __syncthreads();

    float acc = 0.f;
    if (!diag) {
        // cross tile: j = h*64 .. h*64+63, wave-uniform -> b128 broadcast
        const int j0 = h * 64;
        #pragma unroll 8
        for (int jj = 0; jj < 64; ++jj) {
            const float4 a = sj[j0 + jj];
            const float dx = xi - a.x, dy = yi - a.y, dz = zi - a.z;
            const float ds = fmaf(dx,dx, fmaf(dy,dy, fmaf(dz,dz, 1e-8f)));
            const float v  = fmaxf(MIN_D - __builtin_amdgcn_sqrtf(ds), 0.f);
            acc = fmaf(v, v, acc);
        }
    } else {
        // diagonal tile: j = i + d; h=0: d=1..64, h=1: d=65..127 (disjoint)
        const int d0 = h ? 65 : 1;
        const int nd = h ? 63 : 64;        // wave-uniform trip count
        for (int k = 0; k < nd; ++k) {
            const int jj = l + d0 + k;     // per-lane, consecutive across lanes
            const float4 a = sj[jj & (TILE - 1)];
            const float dx = xi - a.x, dy = yi - a.y, dz = zi - a.z;
            const float ds = fmaf(dx,dx, fmaf(dy,dy, fmaf(dz,dz, 1e-8f)));
            const float v  = fmaxf(MIN_D - __builtin_amdgcn_sqrtf(ds), 0.f);
            float c = v * v;
            if (jj >= TILE) c = 0.f;       // mask out-of-tile
            acc += c;
        }
    }

    // wave butterfly, then block reduce
    #pragma unroll
    for (int off = 1; off < 64; off <<= 1)
        acc += __shfl_xor(acc, off, 64);

    __shared__ float wsum[4];
    if ((t & 63) == 0) wsum[t >> 6] = acc;
    __syncthreads();
    if (t == 0) {
        const float s = (wsum[0] + wsum[1]) + (wsum[2] + wsum[3]);
        partials[b * NPAIR + p] = s;
    }
}

__global__ __launch_bounds__(256)
void reduce_kernel(const float* __restrict__ partials, float* __restrict__ out)
{
    const int tid = threadIdx.x;
    float s = 0.f;
    for (int k = tid; k < NPART; k += 256) s += partials[k];
    #pragma unroll
    for (int off = 1; off < 64; off <<= 1)
        s += __shfl_xor(s, off, 64);
    __shared__ float wsum[4];
    if ((tid & 63) == 0) wsum[tid >> 6] = s;
    __syncthreads();
    if (tid == 0) {
        const float tot = (wsum[0] + wsum[1]) + (wsum[2] + wsum[3]);
        out[0] = tot * (1.0f / (float)NB);   // each pair counted once
    }
}

extern "C" void kernel_launch(void* const* d_in, const int* in_sizes, int n_in,
                              void* d_out, int out_size, void* d_ws, size_t ws_size,
                              hipStream_t stream)
{
    const float* coords = (const float*)d_in[0];
    float* partials = (float*)d_ws;
    float* out = (float*)d_out;

    dim3 grid(NB, NPAIR);   // 64 x 36 = 2304 blocks
    pair_kernel<<<grid, 256, 0, stream>>>(coords, partials);
    reduce_kernel<<<1, 256, 0, stream>>>(partials, out);
}